// Round 1
// baseline (436.724 us; speedup 1.0000x reference)
//
#include <hip/hip_runtime.h>

// CRY gate, DIM=2, N=24, C=0, T=1, J=1, K=2, B=2.
// d = g*2^23 + t*2^22 + s (big-endian digits), flat = d*2 + batch.
// Merged index i = 2s+batch in [0, 2^23): contiguous within each (g,t) quadrant.
// Quadrant strides (floats): t -> 2^23, g -> 2^24. Output real at 0, imag at 2^25.
// g=0: identity copy. g=1: [out_t0; out_t1] = [[c,-s],[-s,c]] [in_t0; in_t1],
// applied identically to real and imag parts (matrix is real).

__global__ __launch_bounds__(256) void cry_kernel(
    const float* __restrict__ xr_, const float* __restrict__ xi_,
    const float* __restrict__ ang_, float* __restrict__ out_)
{
    const unsigned tid = blockIdx.x * 256u + threadIdx.x;   // [0, 2^21) float4 units

    float sv, cv;
    __sincosf(0.5f * ang_[0], &sv, &cv);

    const float4* xr  = (const float4*)xr_;
    const float4* xi  = (const float4*)xi_;
    float4*       out = (float4*)out_;

    const unsigned Q  = 1u << 21;  // target-bit stride, float4 units (2^23 floats / 4)
    const unsigned CS = 1u << 22;  // control-bit stride, float4 units (2^24 floats / 4)
    const unsigned IM = 1u << 23;  // imag-half offset in out, float4 units (2^25 floats / 4)

    // ---- control = 0: identity (pure copy) ----
    out[tid]           = xr[tid];
    out[tid + Q]       = xr[tid + Q];
    out[IM + tid]      = xi[tid];
    out[IM + tid + Q]  = xi[tid + Q];

    // ---- control = 1: rotate target (levels 0,1) by theta/2 ----
    {
        // real part
        float4 a = xr[CS + tid];
        float4 b = xr[CS + tid + Q];
        float4 r0, r1;
        r0.x = cv * a.x - sv * b.x;  r1.x = cv * b.x - sv * a.x;
        r0.y = cv * a.y - sv * b.y;  r1.y = cv * b.y - sv * a.y;
        r0.z = cv * a.z - sv * b.z;  r1.z = cv * b.z - sv * a.z;
        r0.w = cv * a.w - sv * b.w;  r1.w = cv * b.w - sv * a.w;
        out[CS + tid]     = r0;
        out[CS + tid + Q] = r1;

        // imag part
        a = xi[CS + tid];
        b = xi[CS + tid + Q];
        r0.x = cv * a.x - sv * b.x;  r1.x = cv * b.x - sv * a.x;
        r0.y = cv * a.y - sv * b.y;  r1.y = cv * b.y - sv * a.y;
        r0.z = cv * a.z - sv * b.z;  r1.z = cv * b.z - sv * a.z;
        r0.w = cv * a.w - sv * b.w;  r1.w = cv * b.w - sv * a.w;
        out[IM + CS + tid]     = r0;
        out[IM + CS + tid + Q] = r1;
    }
}

extern "C" void kernel_launch(void* const* d_in, const int* in_sizes, int n_in,
                              void* d_out, int out_size, void* d_ws, size_t ws_size,
                              hipStream_t stream) {
    const float* xr  = (const float*)d_in[0];
    const float* xi  = (const float*)d_in[1];
    const float* ang = (const float*)d_in[2];
    float* out = (float*)d_out;

    // 2^21 threads, each handling one float4 per (g,t,part) octant
    const int threads = 256;
    const int blocks  = (1u << 21) / threads;  // 8192
    cry_kernel<<<blocks, threads, 0, stream>>>(xr, xi, ang, out);
}